// Round 5
// baseline (390.747 us; speedup 1.0000x reference)
//
#include <hip/hip_runtime.h>
#include <math.h>

#define TT 32
#define EPSF 1e-9f

constexpr int BLOCK = 256;
constexpr int GRID  = 2048;   // N/GRID = 1024 rows per block (contiguous slab)

// Pure-VALU cross-lane moves via DPP (no DS pipe):
//   QX1 = quad_perm [1,0,3,2] (lane^1), QX2 = quad_perm [2,3,0,1] (lane^2),
//   HMIR = row_half_mirror (lane -> lane^7 within each 8-lane group; after the
//   two quad stages every lane of a quad holds the quad total, so combining
//   with any lane of the other quad completes the 8-lane reduction).
template <int CTRL>
__device__ __forceinline__ float dpp_mov(float x) {
    return __int_as_float(__builtin_amdgcn_update_dpp(
        0, __float_as_int(x), CTRL, 0xF, 0xF, true));
}
#define QX1  0xB1
#define QX2  0x4E
#define HMIR 0x141

__device__ __forceinline__ float red8_max(float x) {
    x = fmaxf(x, dpp_mov<QX1>(x));
    x = fmaxf(x, dpp_mov<QX2>(x));
    x = fmaxf(x, dpp_mov<HMIR>(x));
    return x;
}
__device__ __forceinline__ float red8_add(float x) {
    x += dpp_mov<QX1>(x);
    x += dpp_mov<QX2>(x);
    x += dpp_mov<HMIR>(x);
    return x;
}

// One row, 8 lanes per row, lane j owns elems [4j, 4j+4).
__device__ __forceinline__ void process_row8(
    float4 a, int2 t2, float sw,
    const float* __restrict__ w_sh, const float* __restrict__ wcm_sh,
    int base, float& acc_loss, float& acc_sw)
{
    float m = fmaxf(fmaxf(a.x, a.y), fmaxf(a.z, a.w));
    m = red8_max(m);

    float e0 = __expf(a.x - m), e1 = __expf(a.y - m);
    float e2 = __expf(a.z - m), e3 = __expf(a.w - m);
    float s0 = e0, s1 = s0 + e1, s2 = s1 + e2, s3 = s2 + e3;

    float z   = red8_add(s3);
    float inv = __builtin_amdgcn_rcpf(z);

    int d   = t2.x < 0 ? 0 : (t2.x > TT - 1 ? TT - 1 : t2.x);
    int idx = d - base;           // in-lane index of d, may be outside [0,4)

    float pd_e = 0.f;
    pd_e = (idx == 0) ? e0 : pd_e;
    pd_e = (idx == 1) ? e1 : pd_e;
    pd_e = (idx == 2) ? e2 : pd_e;
    pd_e = (idx == 3) ? e3 : pd_e;

    float cdf_e = 0.f;
    cdf_e = (idx >= 0) ? s0 : cdf_e;
    cdf_e = (idx >= 1) ? s1 : cdf_e;
    cdf_e = (idx >= 2) ? s2 : cdf_e;
    cdf_e = (idx >= 3) ? s3 : cdf_e;

    pd_e  = red8_add(pd_e);
    cdf_e = red8_add(cdf_e);

    float p_d = pd_e * inv;
    float Sd  = fminf(fmaxf(1.0f - cdf_e * inv, EPSF), 1.0f);

    bool  ev   = (t2.y != 0);
    float parg = ev ? p_d : Sd;
    float wt   = ev ? w_sh[d] : wcm_sh[d];

    acc_loss = fmaf(-__logf(parg) * wt, sw, acc_loss);
    acc_sw  += sw;
}

// Contiguous-slab layout: block b owns rows [b*per_block, ...); each 8-lane
// group streams rows sequentially (4 KB sequential per group, 128 KB window
// per block) -> DRAM row-buffer friendly, unlike the 16 MB grid-stride jumps.
__global__ __launch_bounds__(BLOCK) void nll_partial(
    const float* __restrict__ preds,
    const int*   __restrict__ targets,
    const float* __restrict__ weight,
    const float* __restrict__ sample_weight,
    double*      __restrict__ partials,
    int N)
{
    __shared__ float w_sh[TT];
    __shared__ float wcm_sh[TT];
    __shared__ double red_l[BLOCK / 64];
    __shared__ double red_s[BLOCK / 64];

    const int tid = threadIdx.x;

    if (tid < TT) w_sh[tid] = weight[tid];
    __syncthreads();
    if (tid < TT) {
        float s = 0.f;
        for (int t = 0; t <= tid; ++t) s += w_sh[t];
        wcm_sh[tid] = s / (float)(tid + 1);
    }
    __syncthreads();

    const int j    = tid & 7;        // lane within 8-lane row group
    const int grp  = tid >> 3;       // group id within block [0, 32)
    const int base = 4 * j;

    const long long per_block = ((long long)N + gridDim.x - 1) / gridDim.x;
    const long long slab0 = (long long)blockIdx.x * per_block;
    const long long slab1 = (slab0 + per_block < (long long)N) ? slab0 + per_block
                                                               : (long long)N;
    const long long rpg = (per_block + (BLOCK / 8) - 1) / (BLOCK / 8);
    long long r0 = slab0 + (long long)grp * rpg;
    long long r1 = r0 + rpg;
    if (r1 > slab1) r1 = slab1;

    float acc_loss = 0.f;
    float acc_sw   = 0.f;

    const float4* preds4   = (const float4*)preds;
    const int2*   targets2 = (const int2*)targets;

    for (long long row = r0; row < r1; row += 2) {
        const bool has2 = (row + 1) < r1;
        const long long rb = has2 ? row + 1 : row;   // safe duplicate on tail

        float4 a0 = preds4[row * 8 + j];
        float4 a1 = preds4[rb * 8 + j];
        int2 t20  = targets2[row];
        int2 t21  = targets2[rb];
        float sw0 = sample_weight[row];
        float sw1 = has2 ? sample_weight[rb] : 0.f;  // sw=0 kills dup contribution

        process_row8(a0, t20, sw0, w_sh, wcm_sh, base, acc_loss, acc_sw);
        process_row8(a1, t21, sw1, w_sh, wcm_sh, base, acc_loss, acc_sw);
    }

    // block reduction (x8 lane duplication; scale by 1/8)
    double dl = (double)acc_loss;
    double ds = (double)acc_sw;
    for (int mask = 1; mask < 64; mask <<= 1) {
        dl += __shfl_xor(dl, mask);
        ds += __shfl_xor(ds, mask);
    }
    dl *= 0.125;
    ds *= 0.125;

    const int lane = tid & 63;
    const int w    = tid >> 6;
    if (lane == 0) { red_l[w] = dl; red_s[w] = ds; }
    __syncthreads();
    if (tid == 0) {
        double L = 0.0, S = 0.0;
        for (int i = 0; i < BLOCK / 64; ++i) { L += red_l[i]; S += red_s[i]; }
        partials[2 * (long long)blockIdx.x + 0] = L;
        partials[2 * (long long)blockIdx.x + 1] = S;
    }
}

// Kernel 2: reduce per-block partials, finalize scalar.
__global__ __launch_bounds__(256) void nll_final(
    const double* __restrict__ partials, int nblocks, float* __restrict__ out)
{
    const int tid = threadIdx.x;
    double sl = 0.0, ss = 0.0;
    for (int i = tid; i < nblocks; i += 256) {
        sl += partials[2 * i + 0];
        ss += partials[2 * i + 1];
    }
    for (int mask = 1; mask < 64; mask <<= 1) {
        sl += __shfl_xor(sl, mask);
        ss += __shfl_xor(ss, mask);
    }
    __shared__ double s_l[4], s_s[4];
    const int w = tid >> 6;
    if ((tid & 63) == 0) { s_l[w] = sl; s_s[w] = ss; }
    __syncthreads();
    if (tid == 0) {
        double L = 0.0, S = 0.0;
        for (int i = 0; i < 4; ++i) { L += s_l[i]; S += s_s[i]; }
        double denom = S > 1e-9 ? S : 1e-9;
        out[0] = (float)(L / denom);
    }
}

extern "C" void kernel_launch(void* const* d_in, const int* in_sizes, int n_in,
                              void* d_out, int out_size, void* d_ws, size_t ws_size,
                              hipStream_t stream) {
    const float* preds         = (const float*)d_in[0];
    const int*   targets       = (const int*)d_in[1];
    const float* weight        = (const float*)d_in[2];
    const float* sample_weight = (const float*)d_in[3];
    float*       out           = (float*)d_out;
    double*      partials      = (double*)d_ws;

    const int N = in_sizes[3];

    int grid = GRID;
    size_t need = (size_t)grid * 2 * sizeof(double);
    if (ws_size < need) {
        grid = (int)(ws_size / (2 * sizeof(double)));
        if (grid < 1) grid = 1;
    }

    nll_partial<<<grid, BLOCK, 0, stream>>>(preds, targets, weight, sample_weight, partials, N);
    nll_final<<<1, 256, 0, stream>>>(partials, grid, out);
}

// Round 6
// 378.404 us; speedup vs baseline: 1.0326x; 1.0326x over previous
//
#include <hip/hip_runtime.h>
#include <math.h>

#define TT 32
#define EPSF 1e-9f

constexpr int BLOCK = 256;        // 32 rows per block, 8 lanes per row
constexpr int MID_BLOCKS = 64;

// Pure-VALU cross-lane moves via DPP:
//   QX1 = quad_perm [1,0,3,2] (lane^1), QX2 = quad_perm [2,3,0,1] (lane^2),
//   HMIR = row_half_mirror (lane^7 within 8-lane group).
template <int CTRL>
__device__ __forceinline__ float dpp_mov(float x) {
    return __int_as_float(__builtin_amdgcn_update_dpp(
        0, __float_as_int(x), CTRL, 0xF, 0xF, true));
}
#define QX1  0xB1
#define QX2  0x4E
#define HMIR 0x141

__device__ __forceinline__ float red8_max(float x) {
    x = fmaxf(x, dpp_mov<QX1>(x));
    x = fmaxf(x, dpp_mov<QX2>(x));
    x = fmaxf(x, dpp_mov<HMIR>(x));
    return x;
}
__device__ __forceinline__ float red8_add(float x) {
    x += dpp_mov<QX1>(x);
    x += dpp_mov<QX2>(x);
    x += dpp_mov<HMIR>(x);
    return x;
}

// Copy-kernel-shaped: ONE float4 per thread, no per-thread loop. 65,536 blocks;
// latency is hidden by block turnover (same structure as the harness's 84%-peak
// fill/copy kernels), sidestepping the waitcnt-order serialization that made
// every looped variant stall at ~110 us.
__global__ __launch_bounds__(BLOCK) void nll_partial(
    const float* __restrict__ preds,
    const int*   __restrict__ targets,
    const float* __restrict__ weight,
    const float* __restrict__ sample_weight,
    double*      __restrict__ partials,   // [gridDim.x * 2]
    int N)
{
    __shared__ float w_sh[TT];
    __shared__ float wcm_sh[TT];
    __shared__ double red_l[BLOCK / 64];
    __shared__ double red_s[BLOCK / 64];

    const int tid = threadIdx.x;
    const int j   = tid & 7;                         // lane within 8-lane row group
    long long row = (long long)blockIdx.x * (BLOCK / 8) + (tid >> 3);

    const bool valid = row < (long long)N;
    const long long rowc = valid ? row : (long long)N - 1;

    // Issue the data loads FIRST so they overlap the LDS table setup.
    const float4* preds4   = (const float4*)preds;
    const int2*   targets2 = (const int2*)targets;
    float4 a  = preds4[rowc * 8 + j];                // wave: 8 rows = 1 KB contiguous
    int2   t2 = targets2[rowc];
    float  sw = valid ? sample_weight[rowc] : 0.f;   // sw=0 kills OOB contribution

    if (tid < TT) w_sh[tid] = weight[tid];
    __syncthreads();
    if (tid < TT) {
        float s = 0.f;
        for (int t = 0; t <= tid; ++t) s += w_sh[t];
        wcm_sh[tid] = s / (float)(tid + 1);
    }
    __syncthreads();

    // softmax pieces (lane owns elems [4j, 4j+4))
    float m = fmaxf(fmaxf(a.x, a.y), fmaxf(a.z, a.w));
    m = red8_max(m);

    float e0 = __expf(a.x - m), e1 = __expf(a.y - m);
    float e2 = __expf(a.z - m), e3 = __expf(a.w - m);
    float s0 = e0, s1 = s0 + e1, s2 = s1 + e2, s3 = s2 + e3;

    float z   = red8_add(s3);
    float inv = __builtin_amdgcn_rcpf(z);

    int d   = t2.x < 0 ? 0 : (t2.x > TT - 1 ? TT - 1 : t2.x);
    int idx = d - 4 * j;

    float pd_e = 0.f;
    pd_e = (idx == 0) ? e0 : pd_e;
    pd_e = (idx == 1) ? e1 : pd_e;
    pd_e = (idx == 2) ? e2 : pd_e;
    pd_e = (idx == 3) ? e3 : pd_e;

    float cdf_e = 0.f;
    cdf_e = (idx >= 0) ? s0 : cdf_e;
    cdf_e = (idx >= 1) ? s1 : cdf_e;
    cdf_e = (idx >= 2) ? s2 : cdf_e;
    cdf_e = (idx >= 3) ? s3 : cdf_e;

    pd_e  = red8_add(pd_e);
    cdf_e = red8_add(cdf_e);

    float p_d = pd_e * inv;
    float Sd  = fminf(fmaxf(1.0f - cdf_e * inv, EPSF), 1.0f);

    bool  ev   = (t2.y != 0);
    float parg = ev ? p_d : Sd;
    float wt   = ev ? w_sh[d] : wcm_sh[d];

    float acc_loss = -__logf(parg) * wt * sw;   // each row duplicated x8 in the wave
    float acc_sw   = sw;

    // wave butterfly (sums 8 rows x 8 dup), then LDS across the 4 waves
    double dl = (double)acc_loss;
    double ds = (double)acc_sw;
    for (int mask = 1; mask < 64; mask <<= 1) {
        dl += __shfl_xor(dl, mask);
        ds += __shfl_xor(ds, mask);
    }
    dl *= 0.125;
    ds *= 0.125;

    const int lane = tid & 63;
    const int w    = tid >> 6;
    if (lane == 0) { red_l[w] = dl; red_s[w] = ds; }
    __syncthreads();
    if (tid == 0) {
        double L = 0.0, S = 0.0;
        for (int i = 0; i < BLOCK / 64; ++i) { L += red_l[i]; S += red_s[i]; }
        partials[2 * (long long)blockIdx.x + 0] = L;
        partials[2 * (long long)blockIdx.x + 1] = S;
    }
}

// Stage 2: 64 blocks reduce nblocks double2 partials -> 64 double2.
__global__ __launch_bounds__(256) void nll_mid(
    const double2* __restrict__ partials, int n, double2* __restrict__ outp)
{
    const int tid = threadIdx.x;
    double sl = 0.0, ss = 0.0;
    for (int i = blockIdx.x * 256 + tid; i < n; i += gridDim.x * 256) {
        double2 p = partials[i];
        sl += p.x; ss += p.y;
    }
    for (int mask = 1; mask < 64; mask <<= 1) {
        sl += __shfl_xor(sl, mask);
        ss += __shfl_xor(ss, mask);
    }
    __shared__ double s_l[4], s_s[4];
    const int w = tid >> 6;
    if ((tid & 63) == 0) { s_l[w] = sl; s_s[w] = ss; }
    __syncthreads();
    if (tid == 0) {
        double L = 0.0, S = 0.0;
        for (int i = 0; i < 4; ++i) { L += s_l[i]; S += s_s[i]; }
        outp[blockIdx.x] = make_double2(L, S);
    }
}

// Stage 3: single wave folds the 64 mid results and finalizes.
__global__ __launch_bounds__(64) void nll_final(
    const double2* __restrict__ midp, float* __restrict__ out)
{
    const int tid = threadIdx.x;
    double2 p = midp[tid];
    double sl = p.x, ss = p.y;
    for (int mask = 1; mask < 64; mask <<= 1) {
        sl += __shfl_xor(sl, mask);
        ss += __shfl_xor(ss, mask);
    }
    if (tid == 0) {
        double denom = ss > 1e-9 ? ss : 1e-9;
        out[0] = (float)(sl / denom);
    }
}

extern "C" void kernel_launch(void* const* d_in, const int* in_sizes, int n_in,
                              void* d_out, int out_size, void* d_ws, size_t ws_size,
                              hipStream_t stream) {
    const float* preds         = (const float*)d_in[0];
    const int*   targets       = (const int*)d_in[1];
    const float* weight        = (const float*)d_in[2];
    const float* sample_weight = (const float*)d_in[3];
    float*       out           = (float*)d_out;

    const int N = in_sizes[3];

    const int grid = (int)(((long long)N + (BLOCK / 8) - 1) / (BLOCK / 8));  // 65,536

    double*  partials = (double*)d_ws;                               // grid * 16 B
    double2* midp     = (double2*)((char*)d_ws + (size_t)grid * 16); // 64 * 16 B

    nll_partial<<<grid, BLOCK, 0, stream>>>(preds, targets, weight, sample_weight,
                                            partials, N);
    nll_mid<<<MID_BLOCKS, 256, 0, stream>>>((const double2*)partials, grid, midp);
    nll_final<<<1, 64, 0, stream>>>(midp, out);
}